// Round 9
// baseline (115.858 us; speedup 1.0000x reference)
//
#include <hip/hip_runtime.h>
#include <math.h>

#define M_  2
#define B_  256
#define L_  1024
#define K_  4
#define S_  20
#define NR_ 100
#define NTERM 7   // Taylor terms T_1..T_7 ; ||mu*Q||inf <= 0.13 -> rem ~2e-11

typedef float f32x4_t __attribute__((ext_vector_type(4)));

__device__ __forceinline__ float softplusf(float x) {
    return x > 20.0f ? x : log1pf(expf(x));
}

// ---------------------------------------------------------------------------
// Kernel 1: per (m,k), compute normalized Q, store T_n = Q^n/n!, n=1..NTERM.
// ---------------------------------------------------------------------------
__global__ __launch_bounds__(512)
void qpow_kernel(const float* __restrict__ exch,   // (M,K,S,S)
                 const float* __restrict__ equil,  // (M,K,S)
                 float*       __restrict__ Qpow)   // (M,K,NTERM,400)
{
    __shared__ float sQ[400];
    __shared__ float sT[2][400];
    __shared__ float sRow[20];

    const int blk = blockIdx.x;          // mm*K_ + kk
    const int kk = blk % K_;
    const int mm = blk / K_;
    const int tid = threadIdx.x;
    const bool act = tid < 400;
    const int i = tid / 20;
    const int j = tid - i * 20;

    float p[20];
    float Q0 = 0.0f, rowsum = 0.0f;

    if (act) {
        const float* eq = equil + (mm * K_ + kk) * S_;
        float mx = eq[0];
        #pragma unroll
        for (int z = 1; z < 20; ++z) mx = fmaxf(mx, eq[z]);
        float s = 0.0f;
        #pragma unroll
        for (int z = 0; z < 20; ++z) { p[z] = expf(eq[z] - mx); s += p[z]; }
        const float inv = 1.0f / s;
        #pragma unroll
        for (int z = 0; z < 20; ++z) p[z] *= inv;

        const float* Kx = exch + (mm * K_ + kk) * S_ * S_;
        float R = (i == j) ? 0.0f : softplusf(0.5f * (Kx[i * 20 + j] + Kx[j * 20 + i]));
        Q0 = R * p[j];
        sQ[tid] = Q0;
    }
    __syncthreads();

    if (act) {
        rowsum = 0.0f;
        #pragma unroll
        for (int z = 0; z < 20; ++z) rowsum += sQ[i * 20 + z];
        if (j == 0) sRow[i] = rowsum;
    }
    __syncthreads();

    float* Tout = Qpow + (size_t)blk * (NTERM * 400);
    if (act) {
        float mue = 0.0f;
        #pragma unroll
        for (int z = 0; z < 20; ++z) mue += p[z] * sRow[z];
        float q = (Q0 - ((i == j) ? rowsum : 0.0f)) / fmaxf(mue, 1e-16f);
        sQ[tid] = q;
        sT[0][tid] = q;
        Tout[tid] = q;       // T_1 = Q
    }
    __syncthreads();

    int cur = 0;
    for (int n = 2; n <= NTERM; ++n) {
        if (act) {
            float acc = 0.0f;
            #pragma unroll
            for (int z = 0; z < 20; ++z) acc += sT[cur][i * 20 + z] * sQ[z * 20 + j];
            acc /= (float)n;
            sT[cur ^ 1][tid] = acc;
            Tout[(n - 1) * 400 + tid] = acc;   // T_n = Q^n / n!
        }
        __syncthreads();
        cur ^= 1;
    }
}

// ---------------------------------------------------------------------------
// Kernel 2: anc[m,b,l,k*20+s] = sum_z inputs[m,b,l,z] * P[m,ridx[m,b],k,z,s]
// P built in-block into LDS (z-major [z][k*20+s], 6.4 KB) from L2-resident
// Qpow; ONE barrier total; main loop: P frags from LDS, input rows direct
// from global (broadcast-merged), nontemporal coalesced stores -> no store
// drains, no chunk barriers. 2048 blocks x 320 threads; block owns 256 rows;
// thread = (rg, t): 16 rows (rg+16j) x 4 cols, processed as 2 chunks of 8.
// ---------------------------------------------------------------------------
#define SPANR 256
#define TPB3  320

__device__ __forceinline__ void fma4(float4& a, float s, const float4& p) {
    a.x = fmaf(s, p.x, a.x);
    a.y = fmaf(s, p.y, a.y);
    a.z = fmaf(s, p.z, a.z);
    a.w = fmaf(s, p.w, a.w);
}

__device__ __forceinline__ void nt_store4(float* dst, const float4& v) {
    f32x4_t w;
    w.x = v.x; w.y = v.y; w.z = v.z; w.w = v.w;
    __builtin_nontemporal_store(w, (f32x4_t*)dst);
}

__global__ __launch_bounds__(TPB3)
void einsum_kernel(const float* __restrict__ inp,   // (M,B,L,S)
                   const float* __restrict__ Qpow,  // (M,K,NTERM,400)
                   const float* __restrict__ tauk,  // (M,NR)
                   const float* __restrict__ pmrk,  // (M,K)
                   const int*   __restrict__ ridx,  // (M,B)
                   float*       __restrict__ out)   // (M,B,L,K*S)
{
    __shared__ float Pl[20 * 80];          // [z][k*20+s], 6.4 KB

    const int bx      = blockIdx.x;
    const int quarter = bx & 3;            // L_/SPANR = 4
    const int mb      = bx >> 2;           // 0..511
    const int mm      = mb >> 8;
    const int tid     = threadIdx.x;
    const int t       = tid % 20;
    const int rg      = tid / 20;          // 0..15
    const int k       = t / 5;
    const int s0      = (t % 5) * 4;

    const int r = ridx[mb];                // block-uniform

    // ---- build P into LDS: 1600 elements, 5 per thread ----
    {
        const float tau = softplusf(tauk[mm * NR_ + r]);
        #pragma unroll
        for (int q = 0; q < 5; ++q) {
            const int idx = tid + q * TPB3;        // z*80 + kk*20 + j
            const int z   = idx / 80;
            const int rem = idx - z * 80;
            const int kk  = rem / 20;
            const int j   = rem - kk * 20;
            const float mu = tau * softplusf(pmrk[mm * K_ + kk]);
            const float* T = Qpow + ((size_t)(mm * K_ + kk) * NTERM) * 400 + z * 20 + j;
            float acc = (z == j) ? 1.0f : 0.0f;    // identity
            float mp = mu;
            #pragma unroll
            for (int n = 0; n < NTERM; ++n) { acc = fmaf(mp, T[n * 400], acc); mp *= mu; }
            Pl[idx] = acc;
        }
    }
    __syncthreads();                       // the ONLY barrier

    const size_t row0 = (size_t)mb * L_ + (size_t)quarter * SPANR;
    const float* inb = inp + row0 * 20;
    float*       ob  = out + row0 * 80 + k * 20 + s0;
    const float* Pt  = Pl + k * 20 + s0;   // frag base: + z*80 per z

    #pragma unroll 1
    for (int cc = 0; cc < 2; ++cc) {       // 2 chunks x 8 rows = 16 rows
        float4 acc[8];
        #pragma unroll
        for (int r8 = 0; r8 < 8; ++r8) acc[r8] = make_float4(0.f, 0.f, 0.f, 0.f);

        #pragma unroll
        for (int z4 = 0; z4 < 5; ++z4) {
            const float4 p0 = *(const float4*)(Pt + (z4 * 4 + 0) * 80);
            const float4 p1 = *(const float4*)(Pt + (z4 * 4 + 1) * 80);
            const float4 p2 = *(const float4*)(Pt + (z4 * 4 + 2) * 80);
            const float4 p3 = *(const float4*)(Pt + (z4 * 4 + 3) * 80);
            #pragma unroll
            for (int r8 = 0; r8 < 8; ++r8) {
                const int l = rg + (cc * 8 + r8) * 16;
                const float4 av = *(const float4*)(inb + l * 20 + z4 * 4);
                fma4(acc[r8], av.x, p0);
                fma4(acc[r8], av.y, p1);
                fma4(acc[r8], av.z, p2);
                fma4(acc[r8], av.w, p3);
            }
        }

        #pragma unroll
        for (int r8 = 0; r8 < 8; ++r8) {
            const int l = rg + (cc * 8 + r8) * 16;
            nt_store4(ob + (size_t)l * 80, acc[r8]);
        }
    }
}

// ---------------------------------------------------------------------------
extern "C" void kernel_launch(void* const* d_in, const int* in_sizes, int n_in,
                              void* d_out, int out_size, void* d_ws, size_t ws_size,
                              hipStream_t stream) {
    const float* inp   = (const float*)d_in[0];  // (M,B,L,S)
    const float* tauk  = (const float*)d_in[1];  // (M,NR)
    const float* exch  = (const float*)d_in[2];  // (M,K,S,S)
    const float* equil = (const float*)d_in[3];  // (M,K,S)
    const float* pmrk  = (const float*)d_in[4];  // (M,K)
    const int*   ridx  = (const int*)d_in[5];    // (M,B)
    float* outp = (float*)d_out;

    float* Qpow = (float*)d_ws;                  // M*K*NTERM*400*4 = 89.6 KB

    qpow_kernel<<<M_ * K_, 512, 0, stream>>>(exch, equil, Qpow);
    einsum_kernel<<<M_ * B_ * (L_ / SPANR), TPB3, 0, stream>>>(inp, Qpow, tauk, pmrk, ridx, outp);
}

// Round 10
// 57.691 us; speedup vs baseline: 2.0082x; 2.0082x over previous
//
#include <hip/hip_runtime.h>
#include <math.h>

#define M_  2
#define B_  256
#define L_  1024
#define K_  4
#define S_  20
#define NR_ 100
#define NTERM 7   // Taylor terms T_1..T_7 ; ||mu*Q||inf <= 0.13 -> rem ~2e-11

typedef float f32x4_t __attribute__((ext_vector_type(4)));

__device__ __forceinline__ float softplusf(float x) {
    return x > 20.0f ? x : log1pf(expf(x));
}

// ---------------------------------------------------------------------------
// Kernel 1: per (m,k), compute normalized Q, store T_n = Q^n/n!, n=1..NTERM.
// ---------------------------------------------------------------------------
__global__ __launch_bounds__(512)
void qpow_kernel(const float* __restrict__ exch,   // (M,K,S,S)
                 const float* __restrict__ equil,  // (M,K,S)
                 float*       __restrict__ Qpow)   // (M,K,NTERM,400)
{
    __shared__ float sQ[400];
    __shared__ float sT[2][400];
    __shared__ float sRow[20];

    const int blk = blockIdx.x;          // mm*K_ + kk
    const int kk = blk % K_;
    const int mm = blk / K_;
    const int tid = threadIdx.x;
    const bool act = tid < 400;
    const int i = tid / 20;
    const int j = tid - i * 20;

    float p[20];
    float Q0 = 0.0f, rowsum = 0.0f;

    if (act) {
        const float* eq = equil + (mm * K_ + kk) * S_;
        float mx = eq[0];
        #pragma unroll
        for (int z = 1; z < 20; ++z) mx = fmaxf(mx, eq[z]);
        float s = 0.0f;
        #pragma unroll
        for (int z = 0; z < 20; ++z) { p[z] = expf(eq[z] - mx); s += p[z]; }
        const float inv = 1.0f / s;
        #pragma unroll
        for (int z = 0; z < 20; ++z) p[z] *= inv;

        const float* Kx = exch + (mm * K_ + kk) * S_ * S_;
        float R = (i == j) ? 0.0f : softplusf(0.5f * (Kx[i * 20 + j] + Kx[j * 20 + i]));
        Q0 = R * p[j];
        sQ[tid] = Q0;
    }
    __syncthreads();

    if (act) {
        rowsum = 0.0f;
        #pragma unroll
        for (int z = 0; z < 20; ++z) rowsum += sQ[i * 20 + z];
        if (j == 0) sRow[i] = rowsum;
    }
    __syncthreads();

    float* Tout = Qpow + (size_t)blk * (NTERM * 400);
    if (act) {
        float mue = 0.0f;
        #pragma unroll
        for (int z = 0; z < 20; ++z) mue += p[z] * sRow[z];
        float q = (Q0 - ((i == j) ? rowsum : 0.0f)) / fmaxf(mue, 1e-16f);
        sQ[tid] = q;
        sT[0][tid] = q;
        Tout[tid] = q;       // T_1 = Q
    }
    __syncthreads();

    int cur = 0;
    for (int n = 2; n <= NTERM; ++n) {
        if (act) {
            float acc = 0.0f;
            #pragma unroll
            for (int z = 0; z < 20; ++z) acc += sT[cur][i * 20 + z] * sQ[z * 20 + j];
            acc /= (float)n;
            sT[cur ^ 1][tid] = acc;
            Tout[(n - 1) * 400 + tid] = acc;   // T_n = Q^n / n!
        }
        __syncthreads();
        cur ^= 1;
    }
}

// ---------------------------------------------------------------------------
// Kernel 2: P[m,r,k] = I + sum_n mu^n T_n  (linear combo, no matmuls).
// ---------------------------------------------------------------------------
__global__ __launch_bounds__(512)
void pbuild_kernel(const float* __restrict__ Qpow,  // (M,K,NTERM,400)
                   const float* __restrict__ tauk,  // (M,NR)
                   const float* __restrict__ pmrk,  // (M,K)
                   float*       __restrict__ Pws)   // (M,NR,K,400)
{
    const int blk = blockIdx.x;          // mm*NR*K + rr*K + kk
    const int kk = blk % K_;
    const int rr = (blk / K_) % NR_;
    const int mm = blk / (K_ * NR_);
    const int tid = threadIdx.x;
    if (tid >= 400) return;

    const float mu = softplusf(tauk[mm * NR_ + rr]) * softplusf(pmrk[mm * K_ + kk]);
    const float* T = Qpow + ((size_t)(mm * K_ + kk) * NTERM) * 400 + tid;

    float acc = (tid % 21 == 0) ? 1.0f : 0.0f;   // identity
    float mp = mu;
    #pragma unroll
    for (int n = 0; n < NTERM; ++n) { acc = fmaf(mp, T[n * 400], acc); mp *= mu; }
    Pws[(size_t)blk * 400 + tid] = acc;
}

// ---------------------------------------------------------------------------
// Kernel 3: anc[m,b,l,k*20+s] = sum_z inputs[m,b,l,z] * P[m,ridx[m,b],k,z,s]
// Block owns 256 rows, ALL staged in LDS (20 KB) + P (6.4 KB); ONE barrier;
// thread (rg 0..15, t 0..19) computes 16 rows x 4 cols with acc[16] (64 VGPR
// accumulators - not remat-able). P frags read from LDS ONCE per thread
// (20 ds_reads, amortized over 16 rows); input reads are broadcast (20 lanes
// same addr = free). Nontemporal stores, never drained. 2048 blocks.
// ---------------------------------------------------------------------------
#define SPANR 256
#define TPB3  320

__device__ __forceinline__ void fma4(float4& a, float s, const float4& p) {
    a.x = fmaf(s, p.x, a.x);
    a.y = fmaf(s, p.y, a.y);
    a.z = fmaf(s, p.z, a.z);
    a.w = fmaf(s, p.w, a.w);
}

__device__ __forceinline__ void nt_store4(float* dst, const float4& v) {
    f32x4_t w;
    w.x = v.x; w.y = v.y; w.z = v.z; w.w = v.w;
    __builtin_nontemporal_store(w, (f32x4_t*)dst);
}

__global__ __launch_bounds__(TPB3)
void einsum_kernel(const float* __restrict__ inp,  // (M,B,L,S)
                   const float* __restrict__ Pws,  // (M,NR,K,400)
                   const int*   __restrict__ ridx, // (M,B)
                   float*       __restrict__ out)  // (M,B,L,K*S)
{
    __shared__ float Pl[K_ * 400];          // 6400 B   [k][z][s]
    __shared__ float inL[SPANR * 20];       // 20480 B

    const int bx      = blockIdx.x;
    const int quarter = bx & 3;            // L_/SPANR = 4
    const int mb      = bx >> 2;           // 0..511
    const int mm      = mb >> 8;
    const int tid     = threadIdx.x;
    const int t       = tid % 20;
    const int rg      = tid / 20;          // 0..15
    const int k       = t / 5;
    const int s0      = (t % 5) * 4;

    const int r = ridx[mb];                // block-uniform

    // ---- stage P (1600 floats) and 256 input rows (5120 floats), coalesced ----
    {
        const float4* Psrc = (const float4*)(Pws + ((size_t)(mm * NR_ + r) * K_) * 400);
        float4* Pd = (float4*)Pl;
        Pd[tid] = Psrc[tid];
        if (tid < 80) Pd[320 + tid] = Psrc[320 + tid];

        const size_t row0g = (size_t)mb * L_ + (size_t)quarter * SPANR;
        const float4* Isrc = (const float4*)(inp + row0g * 20);
        float4* Id = (float4*)inL;
        #pragma unroll
        for (int q = 0; q < 4; ++q) Id[tid + q * TPB3] = Isrc[tid + q * TPB3];
    }
    __syncthreads();                       // the ONLY barrier

    const size_t row0 = (size_t)mb * L_ + (size_t)quarter * SPANR;
    float* ob = out + row0 * 80 + k * 20 + s0;
    const float* Pk = Pl + k * 400 + s0;   // + z*20 per z

    float4 acc[16];
    #pragma unroll
    for (int rr = 0; rr < 16; ++rr) acc[rr] = make_float4(0.f, 0.f, 0.f, 0.f);

    #pragma unroll
    for (int z4 = 0; z4 < 5; ++z4) {
        const float4 p0 = *(const float4*)(Pk + (z4 * 4 + 0) * 20);
        const float4 p1 = *(const float4*)(Pk + (z4 * 4 + 1) * 20);
        const float4 p2 = *(const float4*)(Pk + (z4 * 4 + 2) * 20);
        const float4 p3 = *(const float4*)(Pk + (z4 * 4 + 3) * 20);
        #pragma unroll
        for (int rr = 0; rr < 16; ++rr) {
            const int l = rg + rr * 16;
            const float4 av = *(const float4*)(inL + l * 20 + z4 * 4);
            fma4(acc[rr], av.x, p0);
            fma4(acc[rr], av.y, p1);
            fma4(acc[rr], av.z, p2);
            fma4(acc[rr], av.w, p3);
        }
    }

    #pragma unroll
    for (int rr = 0; rr < 16; ++rr) {
        const int l = rg + rr * 16;
        nt_store4(ob + (size_t)l * 80, acc[rr]);
    }
}

// ---------------------------------------------------------------------------
extern "C" void kernel_launch(void* const* d_in, const int* in_sizes, int n_in,
                              void* d_out, int out_size, void* d_ws, size_t ws_size,
                              hipStream_t stream) {
    const float* inp   = (const float*)d_in[0];  // (M,B,L,S)
    const float* tauk  = (const float*)d_in[1];  // (M,NR)
    const float* exch  = (const float*)d_in[2];  // (M,K,S,S)
    const float* equil = (const float*)d_in[3];  // (M,K,S)
    const float* pmrk  = (const float*)d_in[4];  // (M,K)
    const int*   ridx  = (const int*)d_in[5];    // (M,B)
    float* outp = (float*)d_out;

    float* Qpow = (float*)d_ws;                          // 89.6 KB
    float* Pws  = Qpow + (size_t)M_ * K_ * NTERM * 400;  // 1.28 MB

    qpow_kernel<<<M_ * K_, 512, 0, stream>>>(exch, equil, Qpow);
    pbuild_kernel<<<M_ * NR_ * K_, 512, 0, stream>>>(Qpow, tauk, pmrk, Pws);
    einsum_kernel<<<M_ * B_ * (L_ / SPANR), TPB3, 0, stream>>>(inp, Pws, ridx, outp);
}